// Round 2
// baseline (367.191 us; speedup 1.0000x reference)
//
#include <hip/hip_runtime.h>
#include <math.h>

// Problem constants (match reference setup_inputs)
constexpr int B = 128, T = 128, F = 2048, KW = 5;
#define ALPHA 0.9f
#define BETA  0.1f
#define DECAY 0.9f
#define GAMMA 0.5f

// One thread per (b,f) series; lanes consecutive in f -> coalesced at each t.
// Two passes over x, NO per-thread conv array (avoids the R0 register spill):
//   pass 1: S = sum_t x[t]  (+ edge samples) -> closed-form sum_t conv[t]
//           -> spatial-attention gate scale
//   pass 2: 5-tap sliding-window conv fused with the LIF recurrence.
__global__ __launch_bounds__(256) void lif_fused_kernel(
    const float* __restrict__ x,        // [B,T,F]
    const float* __restrict__ thr0p,    // scalar
    const float* __restrict__ convw,    // [1,1,KW]
    const float* __restrict__ convb,    // [1]
    const float* __restrict__ sattn,    // [1]
    float* __restrict__ out)            // [B*T*F] spikes ++ [B*F] mem
{
    const int tid = blockIdx.x * blockDim.x + threadIdx.x;
    const int f = tid & (F - 1);
    const int b = tid >> 11;            // tid / F, F = 2048

    const float w0 = convw[0], w1 = convw[1], w2 = convw[2],
                w3 = convw[3], w4 = convw[4];
    const float cb   = convb[0];
    const float thr0 = thr0p[0];
    const float sa   = sattn[0];

    const float* xp = x + (size_t)b * T * F + f;

    // ---- pass 1: sum over time (+ edge samples) ----
    float S = 0.0f;
    float x0 = 0.0f, x1 = 0.0f, xm2 = 0.0f, xm1 = 0.0f;
#pragma unroll
    for (int t = 0; t < T; ++t) {
        float v = xp[(size_t)t * F];
        S += v;
        if (t == 0)     x0  = v;
        if (t == 1)     x1  = v;
        if (t == T - 2) xm2 = v;
        if (t == T - 1) xm1 = v;
    }

    // closed-form sum_t conv[t] under zero ('SAME') padding:
    float csum = w0 * (S - xm2 - xm1)
               + w1 * (S - xm1)
               + w2 * S
               + w3 * (S - x0)
               + w4 * (S - x0 - x1)
               + (float)T * cb;

    const float meanv = csum * (1.0f / (float)T);
    const float z     = sa * meanv;
    const float watt  = 1.0f / (1.0f + expf(-z));
    const float scale = 1.0f + GAMMA * watt;

    // ---- pass 2: sliding-window conv fused with LIF recurrence ----
    const float PI = 3.14159265358979323846f;
    float mem = 0.0f, thr = thr0;
    float h0 = 0.0f, h1 = 0.0f, h2 = 0.0f;
    float* sp = out + (size_t)b * T * F + f;                 // spikes [B,T,F]
    float* mp = out + (size_t)B * T * F + (size_t)b * F + f; // mem [B,F]

    // window registers: a=x[t-2], bb=x[t-1], c=x[t], d=x[t+1], e=x[t+2]
    float a = 0.0f, bb = 0.0f, c = xp[0], d = xp[(size_t)F];
#pragma unroll
    for (int t = 0; t < T; ++t) {
        float e = (t + 2 < T) ? xp[(size_t)(t + 2) * F] : 0.0f;
        float ct = fmaf(w0, a,
                   fmaf(w1, bb,
                   fmaf(w2, c,
                   fmaf(w3, d,
                   fmaf(w4, e, cb)))));
        a = bb; bb = c; c = d; d = e;

        mem = fmaf(DECAY, mem, ct * scale);
        float sarg  = PI * (mem - thr) * 0.5f;
        float spike = 0.5f * (atanf(sarg) * (1.0f / PI) + 0.5f);
        h0 = h1; h1 = h2; h2 = spike;
        float avg = (h0 + h1 + h2) * (1.0f / 3.0f);
        thr = fmaf(ALPHA, thr, fmaf(BETA, avg, (1.0f - ALPHA) * thr0));
        mem = fmaf(-spike, thr, mem);
        sp[(size_t)t * F] = spike;
    }
    *mp = mem;
}

extern "C" void kernel_launch(void* const* d_in, const int* in_sizes, int n_in,
                              void* d_out, int out_size, void* d_ws, size_t ws_size,
                              hipStream_t stream) {
    const float* x     = (const float*)d_in[0];
    const float* thr0  = (const float*)d_in[1];
    const float* convw = (const float*)d_in[2];
    const float* convb = (const float*)d_in[3];
    const float* sattn = (const float*)d_in[4];
    float* out = (float*)d_out;

    const int total = B * F;            // one thread per (b,f)
    const int block = 256;
    const int grid  = total / block;    // 1024 blocks

    lif_fused_kernel<<<grid, block, 0, stream>>>(x, thr0, convw, convb, sattn, out);
}

// Round 3
// 253.903 us; speedup vs baseline: 1.4462x; 1.4462x over previous
//
#include <hip/hip_runtime.h>
#include <math.h>

// Problem constants (match reference setup_inputs)
constexpr int B = 128, T = 128, F = 2048, KW = 5;
#define ALPHA 0.9f
#define BETA  0.1f
#define DECAY 0.9f
#define GAMMA 0.5f

// Minimax atan, |err| ~1e-5 over full range. Dependent chain ~10 ops
// (vs ~30 for ocml atanf with its full-precision divide).
__device__ __forceinline__ float fast_atan(float z) {
    float az  = fabsf(z);
    float inv = __builtin_amdgcn_rcpf(az);       // v_rcp_f32, ~1 ulp
    bool  big = az > 1.0f;
    float r   = big ? inv : az;
    float s   = r * r;
    float p   =            -0.0117212f;
    p = fmaf(p, s,  0.05265332f);
    p = fmaf(p, s, -0.11643287f);
    p = fmaf(p, s,  0.19354346f);
    p = fmaf(p, s, -0.33262347f);
    p = fmaf(p, s,  0.99997726f);
    p = p * r;                                    // atan(r), r in [0,1]
    float res = big ? (1.57079632679f - p) : p;
    return copysignf(res, z);
}

// One thread per (b,f) series; lanes consecutive in f -> coalesced at each t.
// Two passes over x (second pass is LLC-warm), no conv array.
// __launch_bounds__(256,4): cap 128 VGPR -> 4 blocks/CU -> whole grid resident.
__global__ __launch_bounds__(256, 4) void lif_fused_kernel(
    const float* __restrict__ x,        // [B,T,F]
    const float* __restrict__ thr0p,    // scalar
    const float* __restrict__ convw,    // [1,1,KW]
    const float* __restrict__ convb,    // [1]
    const float* __restrict__ sattn,    // [1]
    float* __restrict__ out)            // [B*T*F] spikes ++ [B*F] mem
{
    const int tid = blockIdx.x * blockDim.x + threadIdx.x;
    const int f = tid & (F - 1);
    const int b = tid >> 11;            // tid / F, F = 2048

    const float w0 = convw[0], w1 = convw[1], w2 = convw[2],
                w3 = convw[3], w4 = convw[4];
    const float cb   = convb[0];
    const float thr0 = thr0p[0];
    const float sa   = sattn[0];

    const float* xp = x + (size_t)b * T * F + f;

    // ---- pass 1: sum over time ----
    float S = 0.0f;
#pragma unroll 16
    for (int t = 0; t < T; ++t)
        S += xp[(size_t)t * F];
    // edge samples (L1/LLC hot — just loaded)
    const float x0  = xp[0];
    const float x1  = xp[(size_t)F];
    const float xm2 = xp[(size_t)(T - 2) * F];
    const float xm1 = xp[(size_t)(T - 1) * F];

    // closed-form sum_t conv[t] under zero ('SAME') padding:
    float csum = w0 * (S - xm2 - xm1)
               + w1 * (S - xm1)
               + w2 * S
               + w3 * (S - x0)
               + w4 * (S - x0 - x1)
               + (float)T * cb;

    const float meanv = csum * (1.0f / (float)T);
    const float z     = sa * meanv;
    const float watt  = 1.0f / (1.0f + expf(-z));
    const float scale = 1.0f + GAMMA * watt;

    // ---- pass 2: sliding-window conv fused with LIF recurrence ----
    const float PI     = 3.14159265358979323846f;
    const float INV_PI = 0.31830988618f;
    float mem = 0.0f, thr = thr0;
    float h0 = 0.0f, h1 = 0.0f, h2 = 0.0f;
    float* sp = out + (size_t)b * T * F + f;                 // spikes [B,T,F]
    float* mp = out + (size_t)B * T * F + (size_t)b * F + f; // mem [B,F]

    // window registers: a=x[t-2], bb=x[t-1], c=x[t], d=x[t+1], e=x[t+2]
    float a = 0.0f, bb = 0.0f, c = xp[0], d = xp[(size_t)F];
#pragma unroll 8
    for (int t = 0; t < T; ++t) {
        float e = (t + 2 < T) ? xp[(size_t)(t + 2) * F] : 0.0f;
        float ct = fmaf(w0, a,
                   fmaf(w1, bb,
                   fmaf(w2, c,
                   fmaf(w3, d,
                   fmaf(w4, e, cb)))));
        a = bb; bb = c; c = d; d = e;

        mem = fmaf(DECAY, mem, ct * scale);
        float sarg  = (PI * 0.5f) * (mem - thr);
        float spike = fmaf(fast_atan(sarg), INV_PI * 0.5f, 0.25f);
        h0 = h1; h1 = h2; h2 = spike;
        float avg = (h0 + h1 + h2) * (1.0f / 3.0f);
        thr = fmaf(ALPHA, thr, fmaf(BETA, avg, (1.0f - ALPHA) * thr0));
        mem = fmaf(-spike, thr, mem);
        __builtin_nontemporal_store(spike, &sp[(size_t)t * F]);
    }
    *mp = mem;
}

extern "C" void kernel_launch(void* const* d_in, const int* in_sizes, int n_in,
                              void* d_out, int out_size, void* d_ws, size_t ws_size,
                              hipStream_t stream) {
    const float* x     = (const float*)d_in[0];
    const float* thr0  = (const float*)d_in[1];
    const float* convw = (const float*)d_in[2];
    const float* convb = (const float*)d_in[3];
    const float* sattn = (const float*)d_in[4];
    float* out = (float*)d_out;

    const int total = B * F;            // one thread per (b,f)
    const int block = 256;
    const int grid  = total / block;    // 1024 blocks

    lif_fused_kernel<<<grid, block, 0, stream>>>(x, thr0, convw, convb, sattn, out);
}